// Round 3
// baseline (3404.412 us; speedup 1.0000x reference)
//
#include <hip/hip_runtime.h>

// LateralInhibition: out = inputs * ((inputs @ w1 + b) > 0), w1 = w with zero diag.
// inputs: [M=32768, 512] fp32 row-major; w: [512,512] fp32 row-major (w[k][n]).
// fp32 vector-ALU SGEMM (no fp32 MFMA on CDNA4; k-sequential fp32 fmaf chain is
// REQUIRED for bit-exact gates vs np/BLAS -> absmax 0.0). BM=BN=128 BK=16, 8x8/thread.
// R3: (a) LDS double-buffer -> one barrier per k-tile, no read/write hazard drain;
//     (b) fragment software-pipelining -> ds_read for k+1 issued before FMAs of k,
//         lgkm wait distance = 64 FMAs instead of 0.
//     Per-(m,n) fmaf order over k unchanged -> output bit-identical to R1/R2.

#define NUMD 512
#define BM 128
#define BN 128
#define BK 16
#define TM 8
#define TN 8
#define PAD 4
#define LDA (BM + PAD)
#define LDB (BN + PAD)

__global__ __launch_bounds__(256, 4) void li_gemm_gate(
    const float* __restrict__ A,    // [M, 512]
    const float* __restrict__ W,    // [512, 512]
    const float* __restrict__ bias, // [512]
    float* __restrict__ out,        // [M, 512]
    int M)
{
    __shared__ __align__(16) float As[2][BK][LDA]; // transposed: As[buf][k][m]
    __shared__ __align__(16) float Bs[2][BK][LDB]; // Bs[buf][k][n]

    const int tid  = threadIdx.x;
    // 8x8 lane grid within each wave; 4 waves tiled 2x2 over the 16x16 thread grid.
    const int lane = tid & 63;
    const int wave = tid >> 6;
    const int mg   = (wave >> 1) * 8 + (lane >> 3);  // 0..15 m-group
    const int ng   = (wave & 1) * 8 + (lane & 7);    // 0..15 n-group

    const int m0 = blockIdx.x * BM;
    const int n0 = blockIdx.y * BN;

    // staging index maps
    const int arow = tid >> 1;
    const int acol = (tid & 1) * 8;
    const int brow = tid >> 5;
    const int bcol = (tid & 31) * 4;

    const float* Aptr = A + (size_t)(m0 + arow) * NUMD + acol;
    const float* Wptr = W + (size_t)brow * NUMD + n0 + bcol;

    float acc[TM][TN];
#pragma unroll
    for (int i = 0; i < TM; ++i)
#pragma unroll
        for (int j = 0; j < TN; ++j) acc[i][j] = 0.0f;

    // ---- prologue: load tile 0, zero diag, stage into buffer 0 ----
    float4 ar0 = *(const float4*)(Aptr);
    float4 ar1 = *(const float4*)(Aptr + 4);
    float4 br0 = *(const float4*)(Wptr);
    float4 br1 = *(const float4*)(Wptr + 8 * NUMD);
    {
        int d0 = (0 + brow) - (n0 + bcol);
        if (d0 >= 0 && d0 < 4) ((float*)&br0)[d0] = 0.0f;
        int d1 = (0 + brow + 8) - (n0 + bcol);
        if (d1 >= 0 && d1 < 4) ((float*)&br1)[d1] = 0.0f;
    }
#pragma unroll
    for (int j = 0; j < 4; ++j) {
        As[0][acol + j][arow]     = ((const float*)&ar0)[j];
        As[0][acol + 4 + j][arow] = ((const float*)&ar1)[j];
    }
    *(float4*)&Bs[0][brow][bcol]     = br0;
    *(float4*)&Bs[0][brow + 8][bcol] = br1;
    __syncthreads();

    const int NT = NUMD / BK; // 32
    for (int kt = 0; kt < NT; ++kt) {
        const int p = kt & 1;

        // issue global prefetch of tile kt+1 (vmcnt consumed at staging below)
        if (kt + 1 < NT) {
            Aptr += BK;
            Wptr += BK * NUMD;
            ar0 = *(const float4*)(Aptr);
            ar1 = *(const float4*)(Aptr + 4);
            br0 = *(const float4*)(Wptr);
            br1 = *(const float4*)(Wptr + 8 * NUMD);
        }

        // ---- inner compute on buffer p, fragment-pipelined ----
        const float* basA = &As[p][0][mg * TM];
        const float* basB = &Bs[p][0][ng * TN];
        float4 fa0 = *(const float4*)(basA);
        float4 fa1 = *(const float4*)(basA + 4);
        float4 fb0 = *(const float4*)(basB);
        float4 fb1 = *(const float4*)(basB + 4);
#pragma unroll
        for (int k = 0; k < BK; ++k) {
            float4 na0, na1, nb0, nb1;
            if (k + 1 < BK) {
                const float* ap = basA + (k + 1) * LDA;
                const float* bp = basB + (k + 1) * LDB;
                na0 = *(const float4*)(ap);
                na1 = *(const float4*)(ap + 4);
                nb0 = *(const float4*)(bp);
                nb1 = *(const float4*)(bp + 4);
            }
            float a[TM] = {fa0.x, fa0.y, fa0.z, fa0.w, fa1.x, fa1.y, fa1.z, fa1.w};
            float b[TN] = {fb0.x, fb0.y, fb0.z, fb0.w, fb1.x, fb1.y, fb1.z, fb1.w};
#pragma unroll
            for (int i = 0; i < TM; ++i)
#pragma unroll
                for (int j = 0; j < TN; ++j)
                    acc[i][j] = fmaf(a[i], b[j], acc[i][j]);
            if (k + 1 < BK) {
                fa0 = na0; fa1 = na1; fb0 = nb0; fb1 = nb1;
            }
        }

        // ---- stage tile kt+1 into buffer p^1 (prev reads of p^1 done: barrier of kt-1) ----
        if (kt + 1 < NT) {
            const int kk = (kt + 1) * BK;
            int d0 = (kk + brow) - (n0 + bcol);
            if (d0 >= 0 && d0 < 4) ((float*)&br0)[d0] = 0.0f;
            int d1 = (kk + brow + 8) - (n0 + bcol);
            if (d1 >= 0 && d1 < 4) ((float*)&br1)[d1] = 0.0f;
#pragma unroll
            for (int j = 0; j < 4; ++j) {
                As[p ^ 1][acol + j][arow]     = ((const float*)&ar0)[j];
                As[p ^ 1][acol + 4 + j][arow] = ((const float*)&ar1)[j];
            }
            *(float4*)&Bs[p ^ 1][brow][bcol]     = br0;
            *(float4*)&Bs[p ^ 1][brow + 8][bcol] = br1;
            __syncthreads();
        }
    }

    // epilogue: out[m][n] = in[m][n] * ((acc + b[n]) > 0)
    float bv[TN];
#pragma unroll
    for (int j = 0; j < TN; ++j) bv[j] = bias[n0 + ng * TN + j];

#pragma unroll
    for (int i = 0; i < TM; ++i) {
        const int gm = m0 + mg * TM + i;
        const float* inrow = A + (size_t)gm * NUMD + n0 + ng * TN;
        float4 x0 = *(const float4*)inrow;
        float4 x1 = *(const float4*)(inrow + 4);
        float x[TN] = {x0.x, x0.y, x0.z, x0.w, x1.x, x1.y, x1.z, x1.w};
        float o[TN];
#pragma unroll
        for (int j = 0; j < TN; ++j) {
            float inh = acc[i][j] + bv[j];
            o[j] = (inh > 0.0f) ? x[j] : 0.0f;
        }
        float4 o0 = {o[0], o[1], o[2], o[3]};
        float4 o1 = {o[4], o[5], o[6], o[7]};
        float* orow = out + (size_t)gm * NUMD + n0 + ng * TN;
        *(float4*)orow       = o0;
        *(float4*)(orow + 4) = o1;
    }
}

extern "C" void kernel_launch(void* const* d_in, const int* in_sizes, int n_in,
                              void* d_out, int out_size, void* d_ws, size_t ws_size,
                              hipStream_t stream) {
    const float* A    = (const float*)d_in[0]; // inputs [8*4096, 512]
    const float* W    = (const float*)d_in[1]; // w [512, 512]
    const float* bias = (const float*)d_in[2]; // b [512]
    float* out        = (float*)d_out;

    const int M = in_sizes[0] / NUMD; // 32768
    dim3 grid(M / BM, NUMD / BN);     // (256, 4)
    li_gemm_gate<<<grid, 256, 0, stream>>>(A, W, bias, out, M);
}

// Round 4
// 390.243 us; speedup vs baseline: 8.7238x; 8.7238x over previous
//
#include <hip/hip_runtime.h>

// LateralInhibition: out = inputs * ((inputs @ w1 + b) > 0), w1 = w with zero diag.
// inputs: [M=32768, 512] fp32 row-major; w: [512,512] fp32 (w[k][n]).
//
// R4: LDS-free outer-product SGEMM. R2's 58% VALUBusy plateau was LDS delivery
// bandwidth (4 ds_read_b128/wave/k-step = 4KB delivered ~48 cyc vs 32 cyc VALU
// CU-share -> <=67% ceiling). Here B comes from SGPRs (W rows are wave-uniform ->
// s_load, dual-issues with VALU), A is 1 float/lane/k via per-lane row reads.
// No LDS, no barriers. Diagonal pre-zeroed into d_ws by a prep kernel so the
// hot loop has zero per-(k,n) compares (SALU would bottleneck at 1/cyc/CU).
// Per-(m,n) k-sequential fmaf chain identical to np/BLAS -> absmax 0.0.

#define NUMD 512
#define BN 64     // columns per thread (acc VGPRs)
#define ROWS 256  // rows per block = blockDim.x

__global__ __launch_bounds__(256) void li_prep(const float* __restrict__ W,
                                               float* __restrict__ Wz) {
    const int idx = (blockIdx.x * 256 + threadIdx.x) * 4; // 256 blocks cover 512*512
    const int row = idx >> 9;
    const int col = idx & (NUMD - 1);
    float4 v = *(const float4*)(W + idx);
    const int d = row - col;
    if (d >= 0 && d < 4) ((float*)&v)[d] = 0.0f;
    *(float4*)(Wz + idx) = v;
}

__global__ __launch_bounds__(256) void li_main(const float* __restrict__ A,
                                               const float* __restrict__ Wz,
                                               const float* __restrict__ bias,
                                               float* __restrict__ out, int M) {
    const int t  = threadIdx.x;
    const int m  = blockIdx.x * ROWS + t;
    const int n0 = blockIdx.y * BN;
    const float* __restrict__ Arow = A + (size_t)m * NUMD;

    float acc[BN];
#pragma unroll
    for (int n = 0; n < BN; ++n) acc[n] = 0.0f;

    // A prefetch: 8 floats (2 float4) in flight, one k-chunk ahead
    float4 p0 = *(const float4*)(Arow + 0);
    float4 p1 = *(const float4*)(Arow + 4);

    for (int k8 = 0; k8 < NUMD; k8 += 8) {
        const float4 c0 = p0, c1 = p1;
        if (k8 + 8 < NUMD) {
            p0 = *(const float4*)(Arow + k8 + 8);
            p1 = *(const float4*)(Arow + k8 + 12);
        }
        const float av[8] = {c0.x, c0.y, c0.z, c0.w, c1.x, c1.y, c1.z, c1.w};
#pragma unroll
        for (int kk = 0; kk < 8; ++kk) {
            const float a = av[kk];
            // wave-uniform row pointer -> s_load (merged to s_load_dwordx16)
            const float* __restrict__ wr = Wz + (size_t)(k8 + kk) * NUMD + n0;
#pragma unroll
            for (int n = 0; n < BN; ++n)
                acc[n] = fmaf(a, wr[n], acc[n]);
        }
    }

    // epilogue: out[m][n] = in[m][n] * ((acc + b[n]) > 0)
    const float* __restrict__ xin = Arow + n0;
    float* __restrict__ orow = out + (size_t)m * NUMD + n0;
#pragma unroll
    for (int c = 0; c < BN; c += 4) {
        float4 x = *(const float4*)(xin + c);
        float4 o;
        o.x = ((acc[c + 0] + bias[n0 + c + 0]) > 0.0f) ? x.x : 0.0f;
        o.y = ((acc[c + 1] + bias[n0 + c + 1]) > 0.0f) ? x.y : 0.0f;
        o.z = ((acc[c + 2] + bias[n0 + c + 2]) > 0.0f) ? x.z : 0.0f;
        o.w = ((acc[c + 3] + bias[n0 + c + 3]) > 0.0f) ? x.w : 0.0f;
        *(float4*)(orow + c) = o;
    }
}

extern "C" void kernel_launch(void* const* d_in, const int* in_sizes, int n_in,
                              void* d_out, int out_size, void* d_ws, size_t ws_size,
                              hipStream_t stream) {
    const float* A    = (const float*)d_in[0]; // inputs [8*4096, 512]
    const float* W    = (const float*)d_in[1]; // w [512, 512]
    const float* bias = (const float*)d_in[2]; // b [512]
    float* out        = (float*)d_out;
    float* Wz         = (float*)d_ws;          // 1 MiB scratch: diag-zeroed W

    const int M = in_sizes[0] / NUMD; // 32768

    li_prep<<<(NUMD * NUMD / 4 + 255) / 256, 256, 0, stream>>>(W, Wz);
    dim3 grid(M / ROWS, NUMD / BN); // (128, 8) = 1024 blocks
    li_main<<<grid, 256, 0, stream>>>(A, Wz, bias, out, M);
}